// Round 3
// baseline (174.794 us; speedup 1.0000x reference)
//
#include <hip/hip_runtime.h>
#include <hip/hip_bf16.h>

#define BH    32
#define SEQ   2048
#define DK    64
#define QBLK  128
#define KBLK  64
#define NIT   (SEQ / KBLK)
#define KSTR  72   // LDS row stride in bf16 elems (144 B, 16B-aligned)

typedef short  short8  __attribute__((ext_vector_type(8)));
typedef float  f32x4   __attribute__((ext_vector_type(4)));
typedef float  float4v __attribute__((ext_vector_type(4)));
typedef unsigned short ushort4v __attribute__((ext_vector_type(4)));
typedef unsigned short ushort8v __attribute__((ext_vector_type(8)));

__device__ __forceinline__ unsigned short f2bf(float f) {
    unsigned int u = __builtin_bit_cast(unsigned int, f);
    u += 0x7FFFu + ((u >> 16) & 1u);   // RNE
    return (unsigned short)(u >> 16);
}

#if __has_builtin(__builtin_amdgcn_exp2f)
#define EXP2F(x) __builtin_amdgcn_exp2f(x)
#else
#define EXP2F(x) exp2f(x)
#endif

__global__ __launch_bounds__(512, 4)
void sdpa_kernel(const float* __restrict__ Q, const float* __restrict__ K,
                 const float* __restrict__ V, const float* __restrict__ M,
                 float* __restrict__ O)
{
    __shared__ unsigned short sK [2][KBLK][KSTR];   // K tile [buf][ki][d]
    __shared__ unsigned short sVt[2][DK][KSTR];     // V^T tile [buf][d][ki]
    __shared__ unsigned short sP [8][16][KSTR];     // per-wave P [q_local][ki]

    const int tid  = threadIdx.x;
    const int wave = tid >> 6;
    const int lane = tid & 63;
    const int g    = lane >> 4;
    const int li   = lane & 15;

    const int b  = blockIdx.x;                 // head; all q-blocks of a head on one XCD
    const int qb = blockIdx.y * QBLK;

    const float* Kb = K + (size_t)b * SEQ * DK;
    const float* Vb = V + (size_t)b * SEQ * DK;

    // ---- Q fragment (A-operand), pre-scaled by (1/sqrt(DK)) * log2(e) ----
    const float QSC = 0.125f * 1.44269504f;
    short8 aq[2];
    {
        const size_t qoff = ((size_t)b * SEQ + (qb + wave * 16 + li)) * DK;
        #pragma unroll
        for (int kk = 0; kk < 2; ++kk) {
            const float* qp = Q + qoff + kk * 32 + g * 8;
            float4v q0 = *(const float4v*)(qp);
            float4v q1 = *(const float4v*)(qp + 4);
            #pragma unroll
            for (int i = 0; i < 4; ++i) {
                aq[kk][i]     = (short)f2bf(q0[i] * QSC);
                aq[kk][i + 4] = (short)f2bf(q1[i] * QSC);
            }
        }
    }

    // staging assignments (512 threads)
    const int sr = tid >> 4;            // K: rows sr and sr+32
    const int sc = (tid & 15) * 4;      // K: col base (4 floats)
    const int vd = tid & 63;            // V^T: d
    const int vk = (tid >> 6) * 8;      // V^T: ki base (8 rows)

    const float* kp = Kb + (size_t)sr * DK + sc;
    const float* vp = Vb + (size_t)vk * DK + vd;
    const float* mbase = M + ((size_t)b * SEQ + (qb + wave * 16 + g * 4)) * SEQ + li;

    float4v kr0, kr1;
    float vr[8];

    // ---- prologue: tile 0 -> buf0, then issue tile 1 loads ----
    kr0 = *(const float4v*)(kp);
    kr1 = *(const float4v*)(kp + 32 * DK);
    #pragma unroll
    for (int j = 0; j < 8; ++j) vr[j] = vp[j * DK];

    {
        ushort4v pk0, pk1;
        #pragma unroll
        for (int e = 0; e < 4; ++e) { pk0[e] = f2bf(kr0[e]); pk1[e] = f2bf(kr1[e]); }
        *(ushort4v*)(&sK[0][sr][sc])      = pk0;
        *(ushort4v*)(&sK[0][sr + 32][sc]) = pk1;
        ushort8v pv_;
        #pragma unroll
        for (int e = 0; e < 8; ++e) pv_[e] = f2bf(vr[e]);
        *(ushort8v*)(&sVt[0][vd][vk]) = pv_;
    }
    kp += KBLK * DK;  vp += KBLK * DK;
    kr0 = *(const float4v*)(kp);
    kr1 = *(const float4v*)(kp + 32 * DK);
    #pragma unroll
    for (int j = 0; j < 8; ++j) vr[j] = vp[j * DK];

    __syncthreads();   // buf0 visible

    f32x4 oacc[4] = {};
    float lsum[4] = {0.f, 0.f, 0.f, 0.f};

    for (int it = 0; it < NIT; ++it) {
        const int cb = it & 1;

        // ---- mask loads for THIS tile (issued first) ----
        float mk[4][4];
        {
            const float* mp = mbase + (size_t)it * KBLK;
            #pragma unroll
            for (int r = 0; r < 4; ++r)
                #pragma unroll
                for (int t = 0; t < 4; ++t)
                    mk[r][t] = mp[(size_t)r * SEQ + t * 16];
        }

        // ---- stage tile it+1 into buf[cb^1] (regs loaded one iteration ago) ----
        if (it + 1 < NIT) {
            const int nb = cb ^ 1;
            ushort4v pk0, pk1;
            #pragma unroll
            for (int e = 0; e < 4; ++e) { pk0[e] = f2bf(kr0[e]); pk1[e] = f2bf(kr1[e]); }
            *(ushort4v*)(&sK[nb][sr][sc])      = pk0;
            *(ushort4v*)(&sK[nb][sr + 32][sc]) = pk1;
            ushort8v pv_;
            #pragma unroll
            for (int e = 0; e < 8; ++e) pv_[e] = f2bf(vr[e]);
            *(ushort8v*)(&sVt[nb][vd][vk]) = pv_;

            // ---- issue global loads for tile it+2 ----
            if (it + 2 < NIT) {
                kp += KBLK * DK;  vp += KBLK * DK;
                kr0 = *(const float4v*)(kp);
                kr1 = *(const float4v*)(kp + 32 * DK);
                #pragma unroll
                for (int j = 0; j < 8; ++j) vr[j] = vp[j * DK];
            }
        }

        // ---- S = Q K^T from buf[cb] ----
        f32x4 sacc[4] = {};
        #pragma unroll
        for (int t = 0; t < 4; ++t) {
            #pragma unroll
            for (int kk = 0; kk < 2; ++kk) {
                short8 bk = *(const short8*)(&sK[cb][t * 16 + li][kk * 32 + g * 8]);
                sacc[t] = __builtin_amdgcn_mfma_f32_16x16x32_bf16(aq[kk], bk, sacc[t], 0, 0, 0);
            }
        }

        // ---- max-free softmax: p = exp2(s_scaled * mask) ----
        #pragma unroll
        for (int r = 0; r < 4; ++r) {
            float p0 = EXP2F(sacc[0][r] * mk[r][0]);
            float p1 = EXP2F(sacc[1][r] * mk[r][1]);
            float p2 = EXP2F(sacc[2][r] * mk[r][2]);
            float p3 = EXP2F(sacc[3][r] * mk[r][3]);
            lsum[r] += (p0 + p1) + (p2 + p3);
            sP[wave][g * 4 + r][0 * 16 + li] = f2bf(p0);
            sP[wave][g * 4 + r][1 * 16 + li] = f2bf(p1);
            sP[wave][g * 4 + r][2 * 16 + li] = f2bf(p2);
            sP[wave][g * 4 + r][3 * 16 + li] = f2bf(p3);
        }
        // sP per-wave: wave-internal write->read needs no barrier

        // ---- O += P V from buf[cb] ----
        #pragma unroll
        for (int kk = 0; kk < 2; ++kk) {
            short8 pa = *(const short8*)(&sP[wave][li][kk * 32 + g * 8]);
            #pragma unroll
            for (int dt = 0; dt < 4; ++dt) {
                short8 bv = *(const short8*)(&sVt[cb][dt * 16 + li][kk * 32 + g * 8]);
                oacc[dt] = __builtin_amdgcn_mfma_f32_16x16x32_bf16(pa, bv, oacc[dt], 0, 0, 0);
            }
        }

        __syncthreads();   // end of iteration: buf[cb] reads done, buf[cb^1] writes visible
    }

    // ---- epilogue: reduce row sums across 16-lane group, normalize, store ----
    #pragma unroll
    for (int r = 0; r < 4; ++r) {
        float l = lsum[r];
        l += __shfl_xor(l, 1);
        l += __shfl_xor(l, 2);
        l += __shfl_xor(l, 4);
        l += __shfl_xor(l, 8);
        float inv = 1.0f / l;
        size_t orow = ((size_t)b * SEQ + (qb + wave * 16 + g * 4 + r)) * DK;
        #pragma unroll
        for (int dt = 0; dt < 4; ++dt)
            O[orow + dt * 16 + li] = oacc[dt][r] * inv;
    }
}

extern "C" void kernel_launch(void* const* d_in, const int* in_sizes, int n_in,
                              void* d_out, int out_size, void* d_ws, size_t ws_size,
                              hipStream_t stream) {
    const float* q = (const float*)d_in[0];
    const float* k = (const float*)d_in[1];
    const float* v = (const float*)d_in[2];
    const float* m = (const float*)d_in[3];
    float* o = (float*)d_out;

    // grid.x = head: linear id % 8 == head % 8 -> all q-blocks of a head on one
    // XCD; 4 heads/XCD x 1 MB K/V = 4 MB = L2. 512 WGs = 2 blocks/CU.
    dim3 grid(BH, SEQ / QBLK);
    sdpa_kernel<<<grid, dim3(512), 0, stream>>>(q, k, v, m, o);
}

// Round 4
// 155.467 us; speedup vs baseline: 1.1243x; 1.1243x over previous
//
#include <hip/hip_runtime.h>
#include <hip/hip_bf16.h>

#define BH    32
#define SEQ   2048
#define DK    64
#define QBLK  256
#define KBLK  64
#define NIT   (SEQ / KBLK)
#define KSTR  72   // LDS row stride in bf16 elems (144 B, 16B-aligned)

typedef short  short8  __attribute__((ext_vector_type(8)));
typedef float  f32x4   __attribute__((ext_vector_type(4)));
typedef float  float4v __attribute__((ext_vector_type(4)));
typedef unsigned short ushort4v __attribute__((ext_vector_type(4)));

__device__ __forceinline__ unsigned short f2bf(float f) {
    unsigned int u = __builtin_bit_cast(unsigned int, f);
    u += 0x7FFFu + ((u >> 16) & 1u);   // RNE
    return (unsigned short)(u >> 16);
}

#if __has_builtin(__builtin_amdgcn_exp2f)
#define EXP2F(x) __builtin_amdgcn_exp2f(x)
#else
#define EXP2F(x) exp2f(x)
#endif

__global__ __launch_bounds__(1024, 4)
void sdpa_kernel(const float* __restrict__ Q, const float* __restrict__ K,
                 const float* __restrict__ V, const float* __restrict__ M,
                 float* __restrict__ O)
{
    __shared__ unsigned short sK [KBLK][KSTR];     // K tile [ki][d]
    __shared__ unsigned short sVt[DK][KSTR];       // V^T tile [d][ki]
    __shared__ unsigned short sP [16][16][KSTR];   // per-wave P [q_local][ki]

    const int tid  = threadIdx.x;
    const int wave = tid >> 6;
    const int lane = tid & 63;
    const int g    = lane >> 4;
    const int li   = lane & 15;

    const int b  = blockIdx.x;                 // head; all q-blocks of a head on one XCD
    const int qb = blockIdx.y * QBLK;

    const float* Kb = K + (size_t)b * SEQ * DK;
    const float* Vb = V + (size_t)b * SEQ * DK;

    // ---- Q fragment (A-operand), pre-scaled by (1/sqrt(DK)) * log2(e) ----
    const float QSC = 0.125f * 1.44269504f;
    short8 aq[2];
    {
        const size_t qoff = ((size_t)b * SEQ + (qb + wave * 16 + li)) * DK;
        #pragma unroll
        for (int kk = 0; kk < 2; ++kk) {
            const float* qp = Q + qoff + kk * 32 + g * 8;
            float4v q0 = *(const float4v*)(qp);
            float4v q1 = *(const float4v*)(qp + 4);
            #pragma unroll
            for (int i = 0; i < 4; ++i) {
                aq[kk][i]     = (short)f2bf(q0[i] * QSC);
                aq[kk][i + 4] = (short)f2bf(q1[i] * QSC);
            }
        }
    }

    // staging assignments (1024 threads)
    const int sr = tid >> 4;            // K: row 0..63
    const int sc = (tid & 15) * 4;      // K: col base (4 floats)
    const int vd = tid & 63;            // V^T: d
    const int vk = (tid >> 6) * 4;      // V^T: ki base (4 rows)

    const float* kp = Kb + (size_t)sr * DK + sc;
    const float* vp = Vb + (size_t)vk * DK + vd;
    const float* mbase = M + ((size_t)b * SEQ + (qb + wave * 16 + g * 4)) * SEQ + li;

    // prologue: issue loads for tile 0
    float4v kreg = *(const float4v*)kp;
    float vreg0 = vp[0 * DK], vreg1 = vp[1 * DK], vreg2 = vp[2 * DK], vreg3 = vp[3 * DK];

    f32x4 oacc[4] = {};
    float lsum[4] = {0.f, 0.f, 0.f, 0.f};

    for (int it = 0; it < NIT; ++it) {
        __syncthreads();   // previous compute's LDS reads done
        // ---- write staged K/V tile (waits on in-flight loads) ----
        {
            ushort4v pk;
            pk[0] = f2bf(kreg[0]); pk[1] = f2bf(kreg[1]);
            pk[2] = f2bf(kreg[2]); pk[3] = f2bf(kreg[3]);
            *(ushort4v*)(&sK[sr][sc]) = pk;
            ushort4v pv_;
            pv_[0] = f2bf(vreg0); pv_[1] = f2bf(vreg1);
            pv_[2] = f2bf(vreg2); pv_[3] = f2bf(vreg3);
            *(ushort4v*)(&sVt[vd][vk]) = pv_;
        }
        __syncthreads();

        // ---- mask loads for THIS tile: NON-TEMPORAL (zero reuse -> don't
        //      allocate in L2/L3; keeps K/V cache-resident) ----
        float mk[4][4];
        {
            const float* mp = mbase + (size_t)it * KBLK;
            #pragma unroll
            for (int r = 0; r < 4; ++r)
                #pragma unroll
                for (int t = 0; t < 4; ++t)
                    mk[r][t] = __builtin_nontemporal_load(mp + (size_t)r * SEQ + t * 16);
        }

        // ---- prefetch next K/V tile into regs (normal loads: want caching) ----
        if (it + 1 < NIT) {
            kp += KBLK * DK;  vp += KBLK * DK;
            kreg = *(const float4v*)kp;
            vreg0 = vp[0 * DK]; vreg1 = vp[1 * DK];
            vreg2 = vp[2 * DK]; vreg3 = vp[3 * DK];
        }

        // ---- S = Q K^T ----
        f32x4 sacc[4] = {};
        #pragma unroll
        for (int t = 0; t < 4; ++t) {
            #pragma unroll
            for (int kk = 0; kk < 2; ++kk) {
                short8 bk = *(const short8*)(&sK[t * 16 + li][kk * 32 + g * 8]);
                sacc[t] = __builtin_amdgcn_mfma_f32_16x16x32_bf16(aq[kk], bk, sacc[t], 0, 0, 0);
            }
        }

        // ---- max-free softmax: p = exp2(s_scaled * mask) ----
        #pragma unroll
        for (int r = 0; r < 4; ++r) {
            float p0 = EXP2F(sacc[0][r] * mk[r][0]);
            float p1 = EXP2F(sacc[1][r] * mk[r][1]);
            float p2 = EXP2F(sacc[2][r] * mk[r][2]);
            float p3 = EXP2F(sacc[3][r] * mk[r][3]);
            lsum[r] += (p0 + p1) + (p2 + p3);
            sP[wave][g * 4 + r][0 * 16 + li] = f2bf(p0);
            sP[wave][g * 4 + r][1 * 16 + li] = f2bf(p1);
            sP[wave][g * 4 + r][2 * 16 + li] = f2bf(p2);
            sP[wave][g * 4 + r][3 * 16 + li] = f2bf(p3);
        }
        // sP is per-wave: wave-internal write->read, no barrier needed

        // ---- O += P V ----
        #pragma unroll
        for (int kk = 0; kk < 2; ++kk) {
            short8 pa = *(const short8*)(&sP[wave][li][kk * 32 + g * 8]);
            #pragma unroll
            for (int dt = 0; dt < 4; ++dt) {
                short8 bv = *(const short8*)(&sVt[dt * 16 + li][kk * 32 + g * 8]);
                oacc[dt] = __builtin_amdgcn_mfma_f32_16x16x32_bf16(pa, bv, oacc[dt], 0, 0, 0);
            }
        }
    }

    // ---- epilogue: reduce row sums across the 16-lane group, normalize,
    //      non-temporal store (O has no reuse) ----
    #pragma unroll
    for (int r = 0; r < 4; ++r) {
        float l = lsum[r];
        l += __shfl_xor(l, 1);
        l += __shfl_xor(l, 2);
        l += __shfl_xor(l, 4);
        l += __shfl_xor(l, 8);
        float inv = 1.0f / l;
        size_t orow = ((size_t)b * SEQ + (qb + wave * 16 + g * 4 + r)) * DK;
        #pragma unroll
        for (int dt = 0; dt < 4; ++dt)
            __builtin_nontemporal_store(oacc[dt][r] * inv, O + orow + dt * 16 + li);
    }
}

extern "C" void kernel_launch(void* const* d_in, const int* in_sizes, int n_in,
                              void* d_out, int out_size, void* d_ws, size_t ws_size,
                              hipStream_t stream) {
    const float* q = (const float*)d_in[0];
    const float* k = (const float*)d_in[1];
    const float* v = (const float*)d_in[2];
    const float* m = (const float*)d_in[3];
    float* o = (float*)d_out;

    // grid.x = head so linear dispatch id ≡ head (mod 8): all 8 q-blocks of a
    // head land on one XCD -> K/V (1 MB/head, 4 heads/XCD) stays L2-resident
    // now that the mask stream no longer allocates (nt loads).
    dim3 grid(BH, SEQ / QBLK);
    sdpa_kernel<<<grid, dim3(1024), 0, stream>>>(q, k, v, m, o);
}